// Round 1
// 589.312 us; speedup vs baseline: 1.0265x; 1.0265x over previous
//
#include <hip/hip_runtime.h>
#include <stdint.h>
#include <stddef.h>

// DKVMN: B=64,T=100, DK=DV=N=128, NUM_Q=1000.  f32 in / f32 out (bf16 I/O fails).
// Decomposition v2:
//   kernel A: state-independent w/e/a/ftk for all (b,t); shuffle softmax (8 barriers vs 112).
//   kernel B: Mv recurrence, f32 state in registers, software-pipelined ws loads,
//             nontemporal float4 stores of Mv, AND fused rt-partials:
//             each block reduces w[n]*m[n,d] over its 16 n-rows (shfl_xor + 1 LDS
//             combine, double-buffered -> 1 barrier/step) -> ws_rt (26 MB)
//             so kernel C never re-reads the 419 MB Mv from HBM.
//   kernel C: p from rt partials (4 KB/bt instead of 64 KB/bt), 4 timesteps/block
//             to amortize f_W, shuffle reductions.
// ws usage: 4*WSTRIDE + 8*BT*D floats = 39.3 MB.

constexpr int B = 64;
constexpr int T = 100;
constexpr int D = 128;        // DK = DV = N
constexpr int NUM_Q = 1000;
constexpr int G = 4;          // timesteps per block in kernel A
constexpr int CG = 4;         // timesteps per block in kernel C
constexpr int BT = B * T;     // 6400
constexpr int WSTRIDE = BT * D; // 819200 floats per ws plane

typedef float v4f __attribute__((ext_vector_type(4)));

__device__ __forceinline__ float sigmoidf_(float x) {
  return 1.0f / (1.0f + __expf(-x));
}

// ---------------- Kernel A: per-(b,t) precompute w, e, a, ftk ----------------
__global__ __launch_bounds__(128) void kernelA(
    const int* __restrict__ q, const int* __restrict__ r,
    const float* __restrict__ k_emb, const float* __restrict__ v_emb,
    const float* __restrict__ Mk,
    const float* __restrict__ f_W, const float* __restrict__ f_b,
    const float* __restrict__ e_W, const float* __restrict__ e_b,
    const float* __restrict__ a_W, const float* __restrict__ a_b,
    float* __restrict__ ws_w, float* __restrict__ ws_e,
    float* __restrict__ ws_a, float* __restrict__ ws_f)
{
  const int tid = threadIdx.x;
  const int b  = blockIdx.x / (T / G);
  const int tg = blockIdx.x % (T / G);
  const int tbase = tg * G;

  __shared__ float kt[G][D];
  __shared__ float vt[G][D];
  __shared__ float redm[2], reds[2];

  #pragma unroll
  for (int g = 0; g < G; ++g) {
    int idx = b * T + tbase + g;
    int qi  = q[idx];
    int qri = qi + NUM_Q * r[idx];
    kt[g][tid] = k_emb[qi * D + tid];
    vt[g][tid] = v_emb[qri * D + tid];
  }
  __syncthreads();

  float lg[G], se[G], sa[G], sf[G];
  #pragma unroll
  for (int g = 0; g < G; ++g) { lg[g] = 0.f; se[g] = 0.f; sa[g] = 0.f; sf[g] = 0.f; }

  #pragma unroll 4
  for (int k = 0; k < D; ++k) {
    float mk = Mk[k * D + tid];
    float ew = e_W[k * D + tid];
    float aw = a_W[k * D + tid];
    float fw = f_W[(D + k) * D + tid];   // kt-half of f_W (rows 128..255)
    #pragma unroll
    for (int g = 0; g < G; ++g) {
      float kk = kt[g][k];
      float vv = vt[g][k];
      lg[g] = fmaf(kk, mk, lg[g]);
      se[g] = fmaf(vv, ew, se[g]);
      sa[g] = fmaf(vv, aw, sa[g]);
      sf[g] = fmaf(kk, fw, sf[g]);
    }
  }

  const float eb = e_b[tid];
  const float ab = a_b[tid];
  const float fb = f_b[tid];

  for (int g = 0; g < G; ++g) {
    // softmax over 128 logits: wave shuffle reduce + 2-wave LDS combine
    float v = lg[g];
    #pragma unroll
    for (int s = 32; s > 0; s >>= 1) v = fmaxf(v, __shfl_xor(v, s));
    if ((tid & 63) == 0) redm[tid >> 6] = v;
    __syncthreads();
    float mx = fmaxf(redm[0], redm[1]);
    float ex = __expf(lg[g] - mx);
    v = ex;
    #pragma unroll
    for (int s = 32; s > 0; s >>= 1) v += __shfl_xor(v, s);
    if ((tid & 63) == 0) reds[tid >> 6] = v;
    __syncthreads();
    float sm = reds[0] + reds[1];

    int idx = (b * T + tbase + g) * D + tid;
    ws_w[idx] = ex / sm;
    ws_e[idx] = sigmoidf_(se[g] + eb);
    ws_a[idx] = tanhf(sa[g] + ab);
    ws_f[idx] = sf[g] + fb;
  }
}

// ---------------- Kernel B: Mv scan + fused rt partials ----------------
// block: 256 threads = 16 n-rows x 16 d-groups(8 floats); grid: B x 8 n-tiles
__global__ __launch_bounds__(256) void kernelB(
    const float* __restrict__ Mv0,
    const float* __restrict__ ws_w, const float* __restrict__ ws_e,
    const float* __restrict__ ws_a,
    float* __restrict__ out_Mv, float* __restrict__ ws_rt)
{
  const int b  = blockIdx.x >> 3;
  const int nt = blockIdx.x & 7;
  const int tid = threadIdx.x;
  const int nrow = tid >> 4;
  const int dgrp = tid & 15;
  const int n  = nt * 16 + nrow;
  const int d0 = dgrp * 8;
  const int wave = tid >> 6;
  const int lane = tid & 63;

  // double-buffered partials: [buf][wave][dgrp][8]  (4 KB)
  __shared__ float part[2][4][16][8];

  float m[8];
  #pragma unroll
  for (int i = 0; i < 8; ++i) m[i] = Mv0[n * D + d0 + i];

  const float*  pw = ws_w + (size_t)(b * T) * D + n;
  const float4* pe = (const float4*)(ws_e + (size_t)(b * T) * D + d0);
  const float4* pa = (const float4*)(ws_a + (size_t)(b * T) * D + d0);

  // prologue: load t=0 operands
  float  wv = pw[0];
  float4 e0 = pe[0], e1 = pe[1], a0 = pa[0], a1 = pa[1];

  for (int t = 0; t < T; ++t) {
    // software-pipeline: issue next-step loads before this step's math
    const int tn = (t + 1 < T) ? (t + 1) : t;
    float  wn  = pw[(size_t)tn * D];
    float4 en0 = pe[(size_t)tn * 32], en1 = pe[(size_t)tn * 32 + 1];
    float4 an0 = pa[(size_t)tn * 32], an1 = pa[(size_t)tn * 32 + 1];

    // rt partial from PRE-update state: sum w[n]*m[n,d] over this wave's 4 n-rows
    float pr[8];
    #pragma unroll
    for (int i = 0; i < 8; ++i) pr[i] = wv * m[i];
    #pragma unroll
    for (int i = 0; i < 8; ++i) {
      pr[i] += __shfl_xor(pr[i], 16);
      pr[i] += __shfl_xor(pr[i], 32);
    }
    if (lane < 16) {
      #pragma unroll
      for (int i = 0; i < 8; ++i) part[t & 1][wave][lane][i] = pr[i];
    }

    // state update
    float ee[8] = {e0.x, e0.y, e0.z, e0.w, e1.x, e1.y, e1.z, e1.w};
    float aa[8] = {a0.x, a0.y, a0.z, a0.w, a1.x, a1.y, a1.z, a1.w};
    #pragma unroll
    for (int i = 0; i < 8; ++i) {
      m[i] = m[i] * (1.0f - wv * ee[i]) + wv * aa[i];
    }

    // Mv is never re-read by any kernel now -> nontemporal stores
    size_t obase = ((size_t)(t * B + b) * D + n) * D + d0;
    v4f o0 = {m[0], m[1], m[2], m[3]};
    v4f o1 = {m[4], m[5], m[6], m[7]};
    __builtin_nontemporal_store(o0, (v4f*)(out_Mv + obase));
    __builtin_nontemporal_store(o1, (v4f*)(out_Mv + obase + 4));

    // single barrier per step (double-buffered LDS makes this safe)
    __syncthreads();
    if (tid < D) {
      const int dg = tid >> 3, di = tid & 7;
      float s = part[t & 1][0][dg][di] + part[t & 1][1][dg][di]
              + part[t & 1][2][dg][di] + part[t & 1][3][dg][di];
      ws_rt[((size_t)(b * T + t) * 8 + nt) * D + tid] = s;
    }

    wv = wn; e0 = en0; e1 = en1; a0 = an0; a1 = an1;
  }
}

// ---------------- Kernel C: p from rt partials ----------------
// block: 128 threads, CG=4 timesteps per block; grid: B * T/CG = 1600
__global__ __launch_bounds__(128) void kernelC(
    const float* __restrict__ f_W,
    const float* __restrict__ p_W,
    const float* __restrict__ p_b,
    const float* __restrict__ ws_f, const float* __restrict__ ws_rt,
    float* __restrict__ out_p)
{
  const int grp = blockIdx.x;
  const int b  = grp / (T / CG);
  const int tg = grp % (T / CG);
  const int t0 = tg * CG;
  const int bt0 = b * T + t0;
  const int tid = threadIdx.x;

  __shared__ float rsh[CG][D];
  __shared__ float wred[CG][2];

  float fa[CG];
  #pragma unroll
  for (int g = 0; g < CG; ++g) {
    const float* prt = ws_rt + (size_t)(bt0 + g) * (8 * D);
    float rt = 0.f;
    #pragma unroll
    for (int nt = 0; nt < 8; ++nt) rt += prt[nt * D + tid];
    rsh[g][tid] = rt;
    fa[g] = ws_f[(bt0 + g) * D + tid];   // ftk = kt-half @ f_W + f_b (from A)
  }
  __syncthreads();

  #pragma unroll 4
  for (int d2 = 0; d2 < D; ++d2) {
    float fw = f_W[d2 * D + tid];        // rt-half of f_W (rows 0..127)
    #pragma unroll
    for (int g = 0; g < CG; ++g) fa[g] = fmaf(rsh[g][d2], fw, fa[g]);
  }

  const float pw = p_W[tid];
  #pragma unroll
  for (int g = 0; g < CG; ++g) {
    float v = tanhf(fa[g]) * pw;
    #pragma unroll
    for (int s = 32; s > 0; s >>= 1) v += __shfl_xor(v, s);
    if ((tid & 63) == 0) wred[g][tid >> 6] = v;
  }
  __syncthreads();
  if (tid < CG) {
    float pt = sigmoidf_(wred[tid][0] + wred[tid][1] + p_b[0]);
    out_p[(t0 + tid) * B + b] = pt;
  }
}

extern "C" void kernel_launch(void* const* d_in, const int* in_sizes, int n_in,
                              void* d_out, int out_size, void* d_ws, size_t ws_size,
                              hipStream_t stream)
{
  const int* q = (const int*)d_in[0];
  const int* r = (const int*)d_in[1];
  const float* k_emb = (const float*)d_in[2];
  const float* v_emb = (const float*)d_in[3];
  const float* Mk   = (const float*)d_in[4];
  const float* Mv0  = (const float*)d_in[5];
  const float* f_W  = (const float*)d_in[6];
  const float* f_b  = (const float*)d_in[7];
  const float* p_W  = (const float*)d_in[8];
  const float* p_b  = (const float*)d_in[9];
  const float* e_W  = (const float*)d_in[10];
  const float* e_b  = (const float*)d_in[11];
  const float* a_W  = (const float*)d_in[12];
  const float* a_b  = (const float*)d_in[13];

  float* ws   = (float*)d_ws;
  float* ws_w = ws;
  float* ws_e = ws + (size_t)WSTRIDE;
  float* ws_a = ws + (size_t)2 * WSTRIDE;
  float* ws_f = ws + (size_t)3 * WSTRIDE;
  float* ws_rt = ws + (size_t)4 * WSTRIDE;   // 8 * BT * D floats = 26.2 MB

  float* out    = (float*)d_out;
  float* out_p  = out;            // p: first BT elements, layout (T*B,1)
  float* out_Mv = out + BT;       // Mv: (T*B,128,128)

  hipLaunchKernelGGL(kernelA, dim3(B * (T / G)), dim3(D), 0, stream,
                     q, r, k_emb, v_emb, Mk, f_W, f_b, e_W, e_b, a_W, a_b,
                     ws_w, ws_e, ws_a, ws_f);
  hipLaunchKernelGGL(kernelB, dim3(B * 8), dim3(256), 0, stream,
                     Mv0, ws_w, ws_e, ws_a, out_Mv, ws_rt);
  hipLaunchKernelGGL(kernelC, dim3(B * (T / CG)), dim3(D), 0, stream,
                     f_W, p_W, p_b, ws_f, ws_rt, out_p);
}

// Round 2
// 504.286 us; speedup vs baseline: 1.1995x; 1.1686x over previous
//
#include <hip/hip_runtime.h>
#include <stdint.h>
#include <stddef.h>

// DKVMN: B=64,T=100, DK=DV=N=128, NUM_Q=1000.  f32 in / f32 out (bf16 I/O fails).
// Decomposition v3:
//   kernel A: state-independent w/e/a/ftk for all (b,t); shuffle softmax.
//   kernel B: Mv recurrence. v3 changes (theory: B is latency-bound, not BW-bound):
//     - XCD-aware block swizzle: blockIdx&7 carries b-high, so each XCD's L2
//       (4 MB) holds only its 8 batches' w/e/a planes (1.2 MB) -> per-step
//       loads are L2 hits instead of LLC (~500cy) misses.
//     - m[4] per thread (was m[8]) -> 1024 blocks, 4 waves/SIMD (was 2) ->
//       per-step barrier+latency hidden across 4 independent blocks/CU.
//     - fused rt partials kept: 1 barrier/step, double-buffered LDS, 16
//       partials per (b,t) -> ws_rt (52 MB), C never re-reads the 419 MB Mv.
//   kernel C: p from rt partials (8 KB/bt), 4 timesteps/block, shuffle reduce.
// ws usage: 4*WSTRIDE + 16*BT*D floats = 65.6 MB.

constexpr int B = 64;
constexpr int T = 100;
constexpr int D = 128;        // DK = DV = N
constexpr int NUM_Q = 1000;
constexpr int G = 4;          // timesteps per block in kernel A
constexpr int CG = 4;         // timesteps per block in kernel C
constexpr int BT = B * T;     // 6400
constexpr int WSTRIDE = BT * D; // 819200 floats per ws plane
constexpr int NTILES = 16;    // n-tiles in kernel B (8 rows each)

typedef float v4f __attribute__((ext_vector_type(4)));

__device__ __forceinline__ float sigmoidf_(float x) {
  return 1.0f / (1.0f + __expf(-x));
}

// ---------------- Kernel A: per-(b,t) precompute w, e, a, ftk ----------------
__global__ __launch_bounds__(128) void kernelA(
    const int* __restrict__ q, const int* __restrict__ r,
    const float* __restrict__ k_emb, const float* __restrict__ v_emb,
    const float* __restrict__ Mk,
    const float* __restrict__ f_W, const float* __restrict__ f_b,
    const float* __restrict__ e_W, const float* __restrict__ e_b,
    const float* __restrict__ a_W, const float* __restrict__ a_b,
    float* __restrict__ ws_w, float* __restrict__ ws_e,
    float* __restrict__ ws_a, float* __restrict__ ws_f)
{
  const int tid = threadIdx.x;
  const int b  = blockIdx.x / (T / G);
  const int tg = blockIdx.x % (T / G);
  const int tbase = tg * G;

  __shared__ float kt[G][D];
  __shared__ float vt[G][D];
  __shared__ float redm[2], reds[2];

  #pragma unroll
  for (int g = 0; g < G; ++g) {
    int idx = b * T + tbase + g;
    int qi  = q[idx];
    int qri = qi + NUM_Q * r[idx];
    kt[g][tid] = k_emb[qi * D + tid];
    vt[g][tid] = v_emb[qri * D + tid];
  }
  __syncthreads();

  float lg[G], se[G], sa[G], sf[G];
  #pragma unroll
  for (int g = 0; g < G; ++g) { lg[g] = 0.f; se[g] = 0.f; sa[g] = 0.f; sf[g] = 0.f; }

  #pragma unroll 4
  for (int k = 0; k < D; ++k) {
    float mk = Mk[k * D + tid];
    float ew = e_W[k * D + tid];
    float aw = a_W[k * D + tid];
    float fw = f_W[(D + k) * D + tid];   // kt-half of f_W (rows 128..255)
    #pragma unroll
    for (int g = 0; g < G; ++g) {
      float kk = kt[g][k];
      float vv = vt[g][k];
      lg[g] = fmaf(kk, mk, lg[g]);
      se[g] = fmaf(vv, ew, se[g]);
      sa[g] = fmaf(vv, aw, sa[g]);
      sf[g] = fmaf(kk, fw, sf[g]);
    }
  }

  const float eb = e_b[tid];
  const float ab = a_b[tid];
  const float fb = f_b[tid];

  for (int g = 0; g < G; ++g) {
    // softmax over 128 logits: wave shuffle reduce + 2-wave LDS combine
    float v = lg[g];
    #pragma unroll
    for (int s = 32; s > 0; s >>= 1) v = fmaxf(v, __shfl_xor(v, s));
    if ((tid & 63) == 0) redm[tid >> 6] = v;
    __syncthreads();
    float mx = fmaxf(redm[0], redm[1]);
    float ex = __expf(lg[g] - mx);
    v = ex;
    #pragma unroll
    for (int s = 32; s > 0; s >>= 1) v += __shfl_xor(v, s);
    if ((tid & 63) == 0) reds[tid >> 6] = v;
    __syncthreads();
    float sm = reds[0] + reds[1];

    int idx = (b * T + tbase + g) * D + tid;
    ws_w[idx] = ex / sm;
    ws_e[idx] = sigmoidf_(se[g] + eb);
    ws_a[idx] = tanhf(sa[g] + ab);
    ws_f[idx] = sf[g] + fb;
  }
}

// ---------------- Kernel B: Mv scan + fused rt partials ----------------
// block: 256 threads = 8 n-rows x 32 d-groups(4 floats); grid: 1024 (B x 16 n-tiles)
// XCD swizzle: j&7 = hw XCD -> carries b-high so each XCD sees only 8 batches.
__global__ __launch_bounds__(256) void kernelB(
    const float* __restrict__ Mv0,
    const float* __restrict__ ws_w, const float* __restrict__ ws_e,
    const float* __restrict__ ws_a,
    float* __restrict__ out_Mv, float* __restrict__ ws_rt)
{
  const int j = blockIdx.x;
  const int b  = ((j & 7) << 3) | ((j >> 3) & 7);   // XCD (j&7) owns b in [8*(j&7), +8)
  const int nt = j >> 6;                            // 0..15
  const int tid = threadIdx.x;
  const int nrow = tid >> 5;                        // 0..7
  const int dgrp = tid & 31;                        // 0..31
  const int n  = nt * 8 + nrow;
  const int d0 = dgrp * 4;
  const int wave = tid >> 6;
  const int lane = tid & 63;

  // double-buffered rt partials: [buf][wave][dgrp][4] = 4 KB
  __shared__ float part[2][4][32][4];

  float m[4];
  #pragma unroll
  for (int i = 0; i < 4; ++i) m[i] = Mv0[n * D + d0 + i];

  const float*  pw = ws_w + (size_t)(b * T) * D + n;
  const float4* pe = (const float4*)(ws_e + (size_t)(b * T) * D + d0);
  const float4* pa = (const float4*)(ws_a + (size_t)(b * T) * D + d0);

  // prologue: t=0 operands
  float  wv = pw[0];
  float4 ev = pe[0];
  float4 av = pa[0];

  for (int t = 0; t < T; ++t) {
    // software-pipeline: issue next-step loads before this step's math
    const int tn = (t + 1 < T) ? (t + 1) : t;
    float  wn = pw[(size_t)tn * D];
    float4 en = pe[(size_t)tn * 32];
    float4 an = pa[(size_t)tn * 32];

    // rt partial from PRE-update state: sum w[n]*m[n,d] over this wave's 2 n-rows
    float prx = wv * m[0], pry = wv * m[1], prz = wv * m[2], prw = wv * m[3];
    prx += __shfl_xor(prx, 32);
    pry += __shfl_xor(pry, 32);
    prz += __shfl_xor(prz, 32);
    prw += __shfl_xor(prw, 32);
    if (lane < 32) {
      float4 pr4 = make_float4(prx, pry, prz, prw);
      *(float4*)&part[t & 1][wave][dgrp][0] = pr4;
    }

    // state update
    float ee[4] = {ev.x, ev.y, ev.z, ev.w};
    float aa[4] = {av.x, av.y, av.z, av.w};
    #pragma unroll
    for (int i = 0; i < 4; ++i) {
      m[i] = m[i] * (1.0f - wv * ee[i]) + wv * aa[i];
    }

    // Mv never re-read by any kernel -> nontemporal stream
    size_t obase = ((size_t)(t * B + b) * D + n) * D + d0;
    v4f o0 = {m[0], m[1], m[2], m[3]};
    __builtin_nontemporal_store(o0, (v4f*)(out_Mv + obase));

    // single barrier per step (double-buffered LDS makes this safe)
    __syncthreads();
    if (tid < D) {
      // part[w][tid>>2][tid&3] is addr w*128 + tid -> conflict-free
      float s = part[t & 1][0][tid >> 2][tid & 3]
              + part[t & 1][1][tid >> 2][tid & 3]
              + part[t & 1][2][tid >> 2][tid & 3]
              + part[t & 1][3][tid >> 2][tid & 3];
      ws_rt[((size_t)(b * T + t) * NTILES + nt) * D + tid] = s;
    }

    wv = wn; ev = en; av = an;
  }
}

// ---------------- Kernel C: p from rt partials ----------------
// block: 128 threads, CG=4 timesteps per block; grid: B * T/CG = 1600
__global__ __launch_bounds__(128) void kernelC(
    const float* __restrict__ f_W,
    const float* __restrict__ p_W,
    const float* __restrict__ p_b,
    const float* __restrict__ ws_f, const float* __restrict__ ws_rt,
    float* __restrict__ out_p)
{
  const int grp = blockIdx.x;
  const int b  = grp / (T / CG);
  const int tg = grp % (T / CG);
  const int t0 = tg * CG;
  const int bt0 = b * T + t0;
  const int tid = threadIdx.x;

  __shared__ float rsh[CG][D];
  __shared__ float wred[CG][2];

  float fa[CG];
  #pragma unroll
  for (int g = 0; g < CG; ++g) {
    const float* prt = ws_rt + (size_t)(bt0 + g) * (NTILES * D);
    float rt = 0.f;
    #pragma unroll
    for (int nt = 0; nt < NTILES; ++nt) rt += prt[nt * D + tid];
    rsh[g][tid] = rt;
    fa[g] = ws_f[(bt0 + g) * D + tid];   // ftk = kt-half @ f_W + f_b (from A)
  }
  __syncthreads();

  #pragma unroll 4
  for (int d2 = 0; d2 < D; ++d2) {
    float fw = f_W[d2 * D + tid];        // rt-half of f_W (rows 0..127)
    #pragma unroll
    for (int g = 0; g < CG; ++g) fa[g] = fmaf(rsh[g][d2], fw, fa[g]);
  }

  const float pw = p_W[tid];
  #pragma unroll
  for (int g = 0; g < CG; ++g) {
    float v = tanhf(fa[g]) * pw;
    #pragma unroll
    for (int s = 32; s > 0; s >>= 1) v += __shfl_xor(v, s);
    if ((tid & 63) == 0) wred[g][tid >> 6] = v;
  }
  __syncthreads();
  if (tid < CG) {
    float pt = sigmoidf_(wred[tid][0] + wred[tid][1] + p_b[0]);
    out_p[(t0 + tid) * B + b] = pt;
  }
}

extern "C" void kernel_launch(void* const* d_in, const int* in_sizes, int n_in,
                              void* d_out, int out_size, void* d_ws, size_t ws_size,
                              hipStream_t stream)
{
  const int* q = (const int*)d_in[0];
  const int* r = (const int*)d_in[1];
  const float* k_emb = (const float*)d_in[2];
  const float* v_emb = (const float*)d_in[3];
  const float* Mk   = (const float*)d_in[4];
  const float* Mv0  = (const float*)d_in[5];
  const float* f_W  = (const float*)d_in[6];
  const float* f_b  = (const float*)d_in[7];
  const float* p_W  = (const float*)d_in[8];
  const float* p_b  = (const float*)d_in[9];
  const float* e_W  = (const float*)d_in[10];
  const float* e_b  = (const float*)d_in[11];
  const float* a_W  = (const float*)d_in[12];
  const float* a_b  = (const float*)d_in[13];

  float* ws   = (float*)d_ws;
  float* ws_w = ws;
  float* ws_e = ws + (size_t)WSTRIDE;
  float* ws_a = ws + (size_t)2 * WSTRIDE;
  float* ws_f = ws + (size_t)3 * WSTRIDE;
  float* ws_rt = ws + (size_t)4 * WSTRIDE;   // NTILES * BT * D floats = 52.4 MB

  float* out    = (float*)d_out;
  float* out_p  = out;            // p: first BT elements, layout (T*B,1)
  float* out_Mv = out + BT;       // Mv: (T*B,128,128)

  hipLaunchKernelGGL(kernelA, dim3(B * (T / G)), dim3(D), 0, stream,
                     q, r, k_emb, v_emb, Mk, f_W, f_b, e_W, e_b, a_W, a_b,
                     ws_w, ws_e, ws_a, ws_f);
  hipLaunchKernelGGL(kernelB, dim3(B * NTILES), dim3(256), 0, stream,
                     Mv0, ws_w, ws_e, ws_a, out_Mv, ws_rt);
  hipLaunchKernelGGL(kernelC, dim3(B * (T / CG)), dim3(D), 0, stream,
                     f_W, p_W, p_b, ws_f, ws_rt, out_p);
}